// Round 3
// baseline (3542.813 us; speedup 1.0000x reference)
//
#include <hip/hip_runtime.h>
#include <hip/hip_cooperative_groups.h>
#include <math.h>

#define TSTEPS 63
#define BB 64
#define ED 512
#define HD 1024
#define VV 32000
#define GG 4096            // 4*HD
#define NROWS 4032         // TSTEPS*BB
#define MPAD 4096          // padded row count for MFMA tiles
#define NCH 500            // 64-col LSE chunks (32000/64)
#define HSLOT 65536        // 64*1024 (one h-state slot, shorts)

typedef __attribute__((ext_vector_type(8))) short short8;
typedef __attribute__((ext_vector_type(4))) float f32x4;

__device__ __forceinline__ float sigf(float x) { return 1.0f / (1.0f + __expf(-x)); }

__device__ __forceinline__ short f2bf(float f) {
  unsigned u = __float_as_uint(f);
  unsigned r = (u + 0x7FFFu + ((u >> 16) & 1u)) >> 16;
  return (short)r;
}
__device__ __forceinline__ float bf2f(short h) {
  return __uint_as_float(((unsigned)(unsigned short)h) << 16);
}

#define GLOAD_LDS(g, l) \
  __builtin_amdgcn_global_load_lds((const __attribute__((address_space(1))) void*)(g), \
                                   (__attribute__((address_space(3))) void*)(l), 16, 0, 0)

// ---------------- fp32 -> bf16 convert (4 elems/thread) ----------------
__global__ __launch_bounds__(256)
void cvt_f2b_k(const float* __restrict__ src, short* __restrict__ dst) {
  int i = (blockIdx.x * 256 + threadIdx.x) * 4;
  float4 v = *(const float4*)(src + i);
  short4 o;
  o.x = f2bf(v.x); o.y = f2bf(v.y); o.z = f2bf(v.z); o.w = f2bf(v.w);
  *(short4*)(dst + i) = o;
}

// ---------------- gather emb rows by dec, convert to bf16 ----------------
__global__ __launch_bounds__(256)
void gather_emb_k(const int* __restrict__ dec, const float* __restrict__ emb,
                  short* __restrict__ XembB) {
  int idx = blockIdx.x * 256 + threadIdx.x;
  int r = idx >> 7, cc = (idx & 127) * 4;
  int src = dec[r];
  float4 v = *(const float4*)(emb + (size_t)src * ED + cc);
  short4 o;
  o.x = f2bf(v.x); o.y = f2bf(v.y); o.z = f2bf(v.z); o.w = f2bf(v.w);
  *(short4*)(XembB + (size_t)r * ED + cc) = o;
}

// ---------------- init: h-slots (bf16) + c-states (fp32) ----------------
__global__ __launch_bounds__(256)
void init_state2_k(const float* __restrict__ h0, const float* __restrict__ c0,
                   short* __restrict__ h0buf, short* __restrict__ H1b,
                   float* __restrict__ c0s, float* __restrict__ c1s) {
  int i = blockIdx.x * 256 + threadIdx.x;   // 0..65535
  h0buf[HSLOT + i] = f2bf(h0[i]);           // layer0 h init -> slot 1 (read at t=0)
  H1b[i] = f2bf(h0[BB * HD + i]);           // layer1 h init -> H1 slot -1
  c0s[i] = c0[i];
  c1s[i] = c0[BB * HD + i];
}

__global__ __launch_bounds__(256)
void bias_sum_k(const float* __restrict__ a, const float* __restrict__ b,
                float* __restrict__ s) {
  int i = blockIdx.x * 256 + threadIdx.x;
  s[i] = a[i] + b[i];
}

// ---------------- zero pad rows 4032..4095 of logits-view H1 ----------------
__global__ __launch_bounds__(256)
void pad_h1b_k(short* __restrict__ dst) {
  int i = (blockIdx.x * 256 + threadIdx.x) * 4;
  short4 z; z.x = z.y = z.z = z.w = 0;
  *(short4*)(dst + i) = z;
}

__global__ void zero_out_k(float* __restrict__ out) {
  if (threadIdx.x == 0) out[0] = 0.f;
}

// ---------------- shared MFMA K-loop (validated round 2) ----------------
template<int NK>
__device__ __forceinline__ void mfma_loop(const short* __restrict__ Abase, int lda,
                                          const short* __restrict__ Bbase, int ldb,
                                          short* lds_a, short* lds_b,
                                          f32x4 acc[4][4]) {
  const int tid = threadIdx.x;
  const int l = tid & 63;
  const int w = tid >> 6;
  const int wm = w >> 1, wn = w & 1;
  const int p = tid & 7;
  const int rbase = tid >> 3;

  for (int kt = 0; kt < NK; kt++) {
#pragma unroll
    for (int it = 0; it < 4; it++) {
      int row = it * 32 + rbase;
      int ch = p ^ (row & 7);
      const short* ga = Abase + (size_t)row * lda + kt * 64 + ch * 8;
      const short* gb = Bbase + (size_t)row * ldb + kt * 64 + ch * 8;
      short* la = lds_a + it * 2048 + tid * 8;
      short* lb = lds_b + it * 2048 + tid * 8;
      GLOAD_LDS(ga, la);
      GLOAD_LDS(gb, lb);
    }
    asm volatile("s_waitcnt vmcnt(0)" ::: "memory");
    __syncthreads();

    short8 af[4][2], bf[4][2];
#pragma unroll
    for (int m = 0; m < 4; m++) {
#pragma unroll
      for (int ks = 0; ks < 2; ks++) {
        int ra = wm * 64 + m * 16 + (l & 15);
        int ca = (ks * 4 + (l >> 4)) ^ (ra & 7);
        af[m][ks] = *(const short8*)(lds_a + ra * 64 + ca * 8);
        int rb = wn * 64 + m * 16 + (l & 15);
        int cb = (ks * 4 + (l >> 4)) ^ (rb & 7);
        bf[m][ks] = *(const short8*)(lds_b + rb * 64 + cb * 8);
      }
    }
#pragma unroll
    for (int ks = 0; ks < 2; ks++)
#pragma unroll
      for (int m = 0; m < 4; m++)
#pragma unroll
        for (int n = 0; n < 4; n++)
          acc[m][n] = __builtin_amdgcn_mfma_f32_16x16x32_bf16(af[m][ks], bf[n][ks],
                                                              acc[m][n], 0, 0, 0);
    __syncthreads();
  }
}

// ---------------- X0 = XembB @ Wih0B^T + bih0 + bhh0 (MFMA) ----------------
__global__ __launch_bounds__(256)
void x0_mfma_k(const short* __restrict__ XembB, const short* __restrict__ Wih0B,
               const float* __restrict__ bih0, const float* __restrict__ bhh0,
               float* __restrict__ X0) {
  __shared__ short lds_a[128 * 64];
  __shared__ short lds_b[128 * 64];
  f32x4 acc[4][4];
#pragma unroll
  for (int m = 0; m < 4; m++)
#pragma unroll
    for (int n = 0; n < 4; n++)
#pragma unroll
      for (int q = 0; q < 4; q++) acc[m][n][q] = 0.f;

  mfma_loop<8>(XembB + (size_t)blockIdx.x * 128 * ED, ED,
               Wih0B + (size_t)blockIdx.y * 128 * ED, ED, lds_a, lds_b, acc);

  const int l = threadIdx.x & 63;
  const int w = threadIdx.x >> 6;
  const int wm = w >> 1, wn = w & 1;
#pragma unroll
  for (int m = 0; m < 4; m++)
#pragma unroll
    for (int r = 0; r < 4; r++) {
      int row = blockIdx.x * 128 + wm * 64 + m * 16 + (l >> 4) * 4 + r;
#pragma unroll
      for (int n = 0; n < 4; n++) {
        int col = blockIdx.y * 128 + wn * 64 + n * 16 + (l & 15);
        X0[(size_t)row * GG + col] = acc[m][n][r] + bih0[col] + bhh0[col];
      }
    }
}

// ---------------- persistent cooperative 63-step 2-layer LSTM ----------------
// 96 blocks: 0..31 layer0 (j-slice 32), 32..95 layer1 (j-slice 16), pipelined:
// phase p: layer0(step p) || layer1(step p-1); one grid barrier per phase.
__global__ __launch_bounds__(256, 1)
void recurrence_k(const float* __restrict__ X0, const float* __restrict__ bsum1,
                  const short* __restrict__ Wh0b, const short* __restrict__ Wi1b,
                  const short* __restrict__ Wh1b, short* __restrict__ h0buf,
                  short* __restrict__ H1b, float* __restrict__ c0s,
                  float* __restrict__ c1s) {
  cooperative_groups::grid_group grid = cooperative_groups::this_grid();
  __shared__ short lA[2][4096];   // 64x64 bf16 tile x2
  __shared__ short lB[2][8192];   // 128x64 bf16 tile x2
  const int tid = threadIdx.x;
  const int l   = tid & 63;
  const int w   = tid >> 6;
  const int p8  = tid & 7;
  const int r32 = tid >> 3;
  const int lj  = l & 15;
  const int lh  = l >> 4;
  const bool isA = (blockIdx.x < 32);
  const int g = isA ? (int)blockIdx.x : (int)blockIdx.x - 32;

  for (int ph = 0; ph < 64; ph++) {
    if (isA && ph < TSTEPS) {
      // ======== layer 0, step t: G = h0_prev @ Whh0^T (64x128 slice) ========
      const int t = ph;
      const int jb = g * 32;
      const short* Ab = h0buf + ((t + 1) & 1) * HSLOT;
      f32x4 acc[8];
#pragma unroll
      for (int f = 0; f < 8; f++)
#pragma unroll
        for (int q = 0; q < 4; q++) acc[f][q] = 0.f;

      auto stage0 = [&](int kt, int buf) {
#pragma unroll
        for (int it = 0; it < 2; it++) {
          int row = it * 32 + r32;
          int ch = p8 ^ (row & 7);
          GLOAD_LDS(Ab + (size_t)row * HD + kt * 64 + ch * 8,
                    &lA[buf][it * 2048 + tid * 8]);
        }
#pragma unroll
        for (int it = 0; it < 4; it++) {
          int row = it * 32 + r32;                        // gemm col n (0..127)
          int grow = (row >> 5) * HD + jb + (row & 31);   // Whh0 row
          int ch = p8 ^ (row & 7);
          GLOAD_LDS(Wh0b + (size_t)grow * HD + kt * 64 + ch * 8,
                    &lB[buf][it * 2048 + tid * 8]);
        }
      };

      stage0(0, 0);
      __syncthreads();
      for (int kt = 0; kt < 16; kt++) {
        int cur = kt & 1;
        if (kt < 15) stage0(kt + 1, cur ^ 1);
        int ra = w * 16 + lj;
        short8 af[2];
#pragma unroll
        for (int ks = 0; ks < 2; ks++) {
          int ca = (ks * 4 + lh) ^ (ra & 7);
          af[ks] = *(const short8*)&lA[cur][ra * 64 + ca * 8];
        }
#pragma unroll
        for (int f = 0; f < 8; f++) {
          int rb = f * 16 + lj;
#pragma unroll
          for (int ks = 0; ks < 2; ks++) {
            int cb = (ks * 4 + lh) ^ (rb & 7);
            short8 bfr = *(const short8*)&lB[cur][rb * 64 + cb * 8];
            acc[f] = __builtin_amdgcn_mfma_f32_16x16x32_bf16(af[ks], bfr, acc[f], 0, 0, 0);
          }
        }
        __syncthreads();
      }
      // cell0: add X0 (has x@Wih0^T + both biases), fp32 c-state, write h bf16
      const float* X0t = X0 + (size_t)t * BB * GG;
      short* hdst = h0buf + (t & 1) * HSLOT;
#pragma unroll
      for (int jj = 0; jj < 2; jj++) {
        int j = jb + jj * 16 + lj;
#pragma unroll
        for (int r = 0; r < 4; r++) {
          int b = w * 16 + lh * 4 + r;
          float gi = acc[0 + jj][r] + X0t[(size_t)b * GG + j];
          float gf = acc[2 + jj][r] + X0t[(size_t)b * GG + HD + j];
          float gg = acc[4 + jj][r] + X0t[(size_t)b * GG + 2 * HD + j];
          float go = acc[6 + jj][r] + X0t[(size_t)b * GG + 3 * HD + j];
          float cp = c0s[b * HD + j];
          float cn = sigf(gf) * cp + sigf(gi) * tanhf(gg);
          float hn = sigf(go) * tanhf(cn);
          c0s[b * HD + j] = cn;
          hdst[b * HD + j] = f2bf(hn);
        }
      }
    } else if (!isA && ph >= 1) {
      // ======== layer 1, step t: G = h0n @ Wih1^T + h1_prev @ Whh1^T ========
      const int t = ph - 1;
      const int jb = g * 16;
      f32x4 acc[4];
#pragma unroll
      for (int f = 0; f < 4; f++)
#pragma unroll
        for (int q = 0; q < 4; q++) acc[f][q] = 0.f;

      auto stage1 = [&](int u, int buf) {
        int seg = u >> 4, kt = u & 15;
        const short* Ab = seg ? (H1b + (size_t)t * HSLOT) : (h0buf + (t & 1) * HSLOT);
        const short* Wb = seg ? Wh1b : Wi1b;
#pragma unroll
        for (int it = 0; it < 2; it++) {
          int row = it * 32 + r32;
          int ch = p8 ^ (row & 7);
          GLOAD_LDS(Ab + (size_t)row * HD + kt * 64 + ch * 8,
                    &lA[buf][it * 2048 + tid * 8]);
          int grow = (row >> 4) * HD + jb + (row & 15);   // W row
          GLOAD_LDS(Wb + (size_t)grow * HD + kt * 64 + ch * 8,
                    &lB[buf][it * 2048 + tid * 8]);
        }
      };

      stage1(0, 0);
      __syncthreads();
      for (int u = 0; u < 32; u++) {
        int cur = u & 1;
        if (u < 31) stage1(u + 1, cur ^ 1);
        int ra = w * 16 + lj;
        short8 af[2];
#pragma unroll
        for (int ks = 0; ks < 2; ks++) {
          int ca = (ks * 4 + lh) ^ (ra & 7);
          af[ks] = *(const short8*)&lA[cur][ra * 64 + ca * 8];
        }
#pragma unroll
        for (int f = 0; f < 4; f++) {
          int rb = f * 16 + lj;
#pragma unroll
          for (int ks = 0; ks < 2; ks++) {
            int cb = (ks * 4 + lh) ^ (rb & 7);
            short8 bfr = *(const short8*)&lB[cur][rb * 64 + cb * 8];
            acc[f] = __builtin_amdgcn_mfma_f32_16x16x32_bf16(af[ks], bfr, acc[f], 0, 0, 0);
          }
        }
        __syncthreads();
      }
      // cell1: add combined bias, fp32 c-state, write H1 slot t (bf16)
      int j = jb + lj;
      short* hdst = H1b + (size_t)(t + 1) * HSLOT;
#pragma unroll
      for (int r = 0; r < 4; r++) {
        int b = w * 16 + lh * 4 + r;
        float gi = acc[0][r] + bsum1[j];
        float gf = acc[1][r] + bsum1[HD + j];
        float gg = acc[2][r] + bsum1[2 * HD + j];
        float go = acc[3][r] + bsum1[3 * HD + j];
        float cp = c1s[b * HD + j];
        float cn = sigf(gf) * cp + sigf(gi) * tanhf(gg);
        float hn = sigf(go) * tanhf(cn);
        c1s[b * HD + j] = cn;
        hdst[b * HD + j] = f2bf(hn);
      }
    }
    __threadfence();
    grid.sync();
  }
}

// ---------------- target logit from bf16 H1 ----------------
__global__ __launch_bounds__(256)
void tgt_logit_k(const short* __restrict__ H1log, const float* __restrict__ Wout,
                 const float* __restrict__ bout, const int* __restrict__ dec,
                 float* __restrict__ tl) {
  int gw = (blockIdx.x * 256 + threadIdx.x) >> 6;
  int lane = threadIdx.x & 63;
  if (gw >= NROWS) return;
  int tgt = dec[gw + 64];
  const short* hrow = H1log + (size_t)gw * HD;
  const float* wrow = Wout + (size_t)tgt * HD;
  float s = 0.f;
#pragma unroll
  for (int q = 0; q < 16; q++) {
    int k = lane + q * 64;
    s += bf2f(hrow[k]) * wrow[k];
  }
#pragma unroll
  for (int off = 32; off > 0; off >>= 1) s += __shfl_down(s, off);
  if (lane == 0) tl[gw] = s + bout[tgt];
}

// ---------------- fused logits MFMA GEMM + online LSE (validated round 2) ----
__global__ __launch_bounds__(256)
void lse_mfma_k(const short* __restrict__ H1log, const short* __restrict__ WoutB,
                const float* __restrict__ bout, float* __restrict__ m_part,
                float* __restrict__ s_part) {
  __shared__ short lds_a[128 * 64];
  __shared__ short lds_b[128 * 64];
  f32x4 acc[4][4];
#pragma unroll
  for (int m = 0; m < 4; m++)
#pragma unroll
    for (int n = 0; n < 4; n++)
#pragma unroll
      for (int q = 0; q < 4; q++) acc[m][n][q] = 0.f;

  mfma_loop<16>(H1log + (size_t)blockIdx.x * 128 * HD, HD,
                WoutB + (size_t)blockIdx.y * 128 * HD, HD, lds_a, lds_b, acc);

  const int l = threadIdx.x & 63;
  const int w = threadIdx.x >> 6;
  const int wm = w >> 1, wn = w & 1;
  const int colbase = blockIdx.y * 128 + wn * 64 + (l & 15);
  float bo[4];
#pragma unroll
  for (int n = 0; n < 4; n++) bo[n] = bout[colbase + n * 16];
  const int ch = blockIdx.y * 2 + wn;

#pragma unroll
  for (int m = 0; m < 4; m++) {
#pragma unroll
    for (int r = 0; r < 4; r++) {
      float v0 = acc[m][0][r] + bo[0];
      float v1 = acc[m][1][r] + bo[1];
      float v2 = acc[m][2][r] + bo[2];
      float v3 = acc[m][3][r] + bo[3];
      float mx = fmaxf(fmaxf(v0, v1), fmaxf(v2, v3));
      float s = __expf(v0 - mx) + __expf(v1 - mx) + __expf(v2 - mx) + __expf(v3 - mx);
#pragma unroll
      for (int off = 1; off < 16; off <<= 1) {
        float mo = __shfl_xor(mx, off);
        float so = __shfl_xor(s, off);
        float nm = fmaxf(mx, mo);
        s = s * __expf(mx - nm) + so * __expf(mo - nm);
        mx = nm;
      }
      if ((l & 15) == 0) {
        int row = blockIdx.x * 128 + wm * 64 + m * 16 + (l >> 4) * 4 + r;
        m_part[(size_t)ch * MPAD + row] = mx;
        s_part[(size_t)ch * MPAD + row] = s;
      }
    }
  }
}

// ---------------- per-row LSE merge + loss atomicAdd ----------------
__global__ __launch_bounds__(256)
void row_lse_k(const float* __restrict__ m_part, const float* __restrict__ s_part,
               const float* __restrict__ tl, float* __restrict__ out) {
  int row = blockIdx.x * 256 + threadIdx.x;
  float loss = 0.f;
  if (row < NROWS) {
    float M = -INFINITY, S = 0.f;
    for (int ch = 0; ch < NCH; ch++) {
      float m = m_part[(size_t)ch * MPAD + row];
      float s = s_part[(size_t)ch * MPAD + row];
      float nm = fmaxf(M, m);
      S = S * __expf(M - nm) + s * __expf(m - nm);
      M = nm;
    }
    loss = M + logf(S) - tl[row];
  }
  __shared__ float red[256];
  red[threadIdx.x] = loss;
  __syncthreads();
  for (int s = 128; s > 0; s >>= 1) {
    if (threadIdx.x < s) red[threadIdx.x] += red[threadIdx.x + s];
    __syncthreads();
  }
  if (threadIdx.x == 0) atomicAdd(out, red[0]);
}

extern "C" void kernel_launch(void* const* d_in, const int* in_sizes, int n_in,
                              void* d_out, int out_size, void* d_ws, size_t ws_size,
                              hipStream_t stream) {
  const int*   dec  = (const int*)  d_in[0];
  const float* h0   = (const float*)d_in[2];
  const float* c0   = (const float*)d_in[3];
  const float* emb  = (const float*)d_in[4];
  const float* Wih0 = (const float*)d_in[5];
  const float* Whh0 = (const float*)d_in[6];
  const float* bih0 = (const float*)d_in[7];
  const float* bhh0 = (const float*)d_in[8];
  const float* Wih1 = (const float*)d_in[9];
  const float* Whh1 = (const float*)d_in[10];
  const float* bih1 = (const float*)d_in[11];
  const float* bhh1 = (const float*)d_in[12];
  const float* Wout = (const float*)d_in[13];
  const float* bout = (const float*)d_in[14];
  float* out = (float*)d_out;

  float* ws = (float*)d_ws;
  float* X0     = ws;                                   // 4096*4096 f
  float* m_part = X0 + (size_t)MPAD * GG;               // 500*4096 f
  float* s_part = m_part + (size_t)NCH * MPAD;          // 500*4096 f
  float* tl     = s_part + (size_t)NCH * MPAD;          // 4096 f
  float* c0s    = tl + MPAD;                            // 64*1024 f
  float* c1s    = c0s + BB * HD;                        // 64*1024 f
  float* bsum1  = c1s + BB * HD;                        // 4096 f
  short* H1b    = (short*)(bsum1 + GG);                 // (64+4096rows pad)... 65536+4096*1024 sh
  short* WoutB  = H1b + HSLOT + (size_t)MPAD * HD;      // 32000*1024 sh
  short* Wih0B  = WoutB + (size_t)VV * HD;              // 4096*512 sh
  short* XembB  = Wih0B + (size_t)GG * ED;              // 4096*512 sh
  short* Wh0b   = XembB + (size_t)MPAD * ED;            // 4096*1024 sh
  short* Wi1b   = Wh0b + (size_t)GG * HD;               // 4096*1024 sh
  short* Wh1b   = Wi1b + (size_t)GG * HD;               // 4096*1024 sh
  short* h0buf  = Wh1b + (size_t)GG * HD;               // 2*64*1024 sh
  short* H1log  = H1b + HSLOT;                          // logits A view (4032+64pad rows)

  cvt_f2b_k<<<(VV * HD) / 1024, 256, 0, stream>>>(Wout, WoutB);
  cvt_f2b_k<<<(GG * ED) / 1024, 256, 0, stream>>>(Wih0, Wih0B);
  cvt_f2b_k<<<(GG * HD) / 1024, 256, 0, stream>>>(Whh0, Wh0b);
  cvt_f2b_k<<<(GG * HD) / 1024, 256, 0, stream>>>(Wih1, Wi1b);
  cvt_f2b_k<<<(GG * HD) / 1024, 256, 0, stream>>>(Whh1, Wh1b);
  gather_emb_k<<<(MPAD * ED / 4) / 256, 256, 0, stream>>>(dec, emb, XembB);
  init_state2_k<<<256, 256, 0, stream>>>(h0, c0, h0buf, H1b, c0s, c1s);
  bias_sum_k<<<16, 256, 0, stream>>>(bih1, bhh1, bsum1);
  pad_h1b_k<<<64, 256, 0, stream>>>(H1log + (size_t)NROWS * HD);
  zero_out_k<<<1, 64, 0, stream>>>(out);
  x0_mfma_k<<<dim3(MPAD / 128, GG / 128), 256, 0, stream>>>(XembB, Wih0B, bih0, bhh0, X0);

  void* args[] = {&X0, &bsum1, &Wh0b, &Wi1b, &Wh1b, &h0buf, &H1b, &c0s, &c1s};
  hipLaunchCooperativeKernel((void*)recurrence_k, dim3(96), dim3(256), args, 0, stream);

  tgt_logit_k<<<(NROWS * 64 + 255) / 256, 256, 0, stream>>>(H1log, Wout, bout, dec, tl);
  lse_mfma_k<<<dim3(MPAD / 128, VV / 128), 256, 0, stream>>>(H1log, WoutB, bout, m_part, s_part);
  row_lse_k<<<MPAD / 256, 256, 0, stream>>>(m_part, s_part, tl, out);
}